// Round 4
// baseline (705.831 us; speedup 1.0000x reference)
//
#include <hip/hip_runtime.h>
#include <stdint.h>

#define SQ   2048
#define DIN  4096
#define NH   32
#define NKV  8
#define HD   128
#define NQKV 6144

typedef float f32x4  __attribute__((ext_vector_type(4)));
typedef float f32x16 __attribute__((ext_vector_type(16)));
typedef short bf16x8 __attribute__((ext_vector_type(8)));

__device__ __forceinline__ short f2bf(float f) {
  union { float f; uint32_t u; } v; v.f = f;
  uint32_t r = (v.u + 0x7FFFu + ((v.u >> 16) & 1u)) >> 16;
  return (short)r;
}
__device__ __forceinline__ uint32_t pack2bf(float a, float b) {
  return (uint32_t)(uint16_t)f2bf(a) | ((uint32_t)(uint16_t)f2bf(b) << 16);
}

// async global -> LDS, 16 bytes per lane, dst = lds_base + lane*16 (HW-fixed)
__device__ __forceinline__ void gl2lds(const void* g, void* l) {
  __builtin_amdgcn_global_load_lds(
      (const __attribute__((address_space(1))) void*)g,
      (__attribute__((address_space(3))) void*)l, 16, 0, 0);
}

// ---------------- fp32 -> bf16 elementwise convert ----------------
__global__ void cvt_bf16(const float* __restrict__ src, short* __restrict__ dst, long n) {
  long i = ((long)blockIdx.x * blockDim.x + threadIdx.x) * 4;
  if (i + 3 < n) {
    float4 v = *(const float4*)(src + i);
    short o[4] = { f2bf(v.x), f2bf(v.y), f2bf(v.z), f2bf(v.w) };
    *(uint2*)(dst + i) = *(uint2*)o;
  }
}

// ---------------- tiled transpose + convert ----------------
__global__ __launch_bounds__(256) void transpose_cvt(const float* __restrict__ src, int ldS, long zS,
                                                     short* __restrict__ dst, int ldD, long zD) {
  __shared__ float tile[64][65];
  src += (long)blockIdx.z * zS;
  dst += (long)blockIdx.z * zD;
  int r0 = blockIdx.y * 64, c0 = blockIdx.x * 64;
  int tid = threadIdx.x;
#pragma unroll
  for (int i = 0; i < 16; ++i) {
    int idx = i * 256 + tid;
    int rr = idx >> 6, cc = idx & 63;
    tile[rr][cc] = src[(long)(r0 + rr) * ldS + c0 + cc];
  }
  __syncthreads();
#pragma unroll
  for (int i = 0; i < 16; ++i) {
    int idx = i * 256 + tid;
    int dr = idx >> 6, dc = idx & 63;
    dst[(long)(c0 + dr) * ldD + r0 + dc] = f2bf(tile[dc][dr]);
  }
}

// ---------------- bf16 MFMA GEMM (m97 structure, round-2 proven) ----------------
#define BM 128
#define BN 128
#define BK 32
__global__ __launch_bounds__(256) void gemm_bf16(const short* __restrict__ A, const short* __restrict__ Bt,
                                                 float* __restrict__ C, int M, int N, int K) {
  __shared__ __align__(16) short As[BM * BK];
  __shared__ __align__(16) short Bs[BN * BK];
  int tid = threadIdx.x;
  int wave = tid >> 6, lane = tid & 63;
  int l16 = lane & 15, lq = lane >> 4;
  int m0 = blockIdx.y * BM, n0 = blockIdx.x * BN;
  int wm = (wave >> 1) * 64, wn = (wave & 1) * 64;
  int ch = (lane & 3) ^ ((lane >> 3) & 3);
  f32x4 acc[4][4] = {};
  for (int k0 = 0; k0 < K; k0 += BK) {
#pragma unroll
    for (int c = 0; c < 2; ++c) {
      int call = wave * 2 + c;
      int r = call * 16 + (lane >> 2);
      gl2lds(&A[(long)(m0 + r) * K + k0 + ch * 8], &As[call * 512]);
      gl2lds(&Bt[(long)(n0 + r) * K + k0 + ch * 8], &Bs[call * 512]);
    }
    __syncthreads();
    bf16x8 af[4], bfr[4];
#pragma unroll
    for (int i = 0; i < 4; ++i) {
      int row = wm + i * 16 + l16;
      af[i] = *(const bf16x8*)&As[row * BK + (lq ^ ((row >> 1) & 3)) * 8];
    }
#pragma unroll
    for (int j = 0; j < 4; ++j) {
      int row = wn + j * 16 + l16;
      bfr[j] = *(const bf16x8*)&Bs[row * BK + (lq ^ ((row >> 1) & 3)) * 8];
    }
#pragma unroll
    for (int i = 0; i < 4; ++i)
#pragma unroll
      for (int j = 0; j < 4; ++j)
        acc[i][j] = __builtin_amdgcn_mfma_f32_16x16x32_bf16(af[i], bfr[j], acc[i][j], 0, 0, 0);
    __syncthreads();
  }
#pragma unroll
  for (int i = 0; i < 4; ++i)
#pragma unroll
    for (int j = 0; j < 4; ++j)
#pragma unroll
      for (int r = 0; r < 4; ++r) {
        int row = m0 + wm + i * 16 + lq * 4 + r;
        int col = n0 + wn + j * 16 + l16;
        C[(long)row * N + col] = acc[i][j][r];
      }
}

// ---------------- fused LayerNorm + RoPE (round-2 proven) ----------------
__global__ __launch_bounds__(64) void ln_rope(const float* __restrict__ qkv,
                                              const float* __restrict__ cosb, const float* __restrict__ sinb,
                                              const float* __restrict__ qw, const float* __restrict__ qb,
                                              const float* __restrict__ kw, const float* __restrict__ kb,
                                              short* __restrict__ qo, short* __restrict__ ko) {
  int s = blockIdx.x, slice = blockIdx.y, t = threadIdx.x;
  bool isq = slice < NH;
  int off = isq ? slice * HD : DIN + (slice - NH) * HD;
  const float* src = qkv + (long)s * NQKV + off;
  float v0 = src[t], v1 = src[t + 64];
  float sum = v0 + v1, ss = v0 * v0 + v1 * v1;
#pragma unroll
  for (int o = 1; o < 64; o <<= 1) { sum += __shfl_xor(sum, o); ss += __shfl_xor(ss, o); }
  float mu = sum * (1.f / 128.f);
  float var = ss * (1.f / 128.f) - mu * mu;
  float rstd = rsqrtf(var + 1e-6f);
  const float* w  = isq ? qw : kw;
  const float* bb = isq ? qb : kb;
  float n0 = (v0 - mu) * rstd * w[t]      + bb[t];
  float n1 = (v1 - mu) * rstd * w[t + 64] + bb[t + 64];
  float c0 = cosb[s * HD + t], c1 = cosb[s * HD + t + 64];
  float s0 = sinb[s * HD + t], s1 = sinb[s * HD + t + 64];
  float o0 = n0 * c0 - n1 * s0;
  float o1 = n1 * c1 + n0 * s1;
  short* dst = isq ? (qo + ((long)slice * SQ + s) * HD)
                   : (ko + ((long)(slice - NH) * SQ + s) * HD);
  dst[t] = f2bf(o0);
  dst[t + 64] = f2bf(o1);
}

// ---------------- flash attention v3: LDS-free, barrier-free, 32x32 MFMA ----------------
// Orientation: S^T = K*Q^T and O^T-ish via (PV)^T = V^T * P^T, so scores AND output
// acc have col = q = lane&31 -> per-lane softmax state, in-register key reduction,
// single shfl_xor(32). One 32-row q-strip per wave; K/V/Q frags read direct from
// global (L2); blocks pinned to XCD = group for L2 residency; LPT block order.
#define NEG_INF (-__builtin_inff())

__device__ __forceinline__ void attn_step(const short* __restrict__ kg, const short* __restrict__ vg,
                                          const bf16x8* aq, int kt, int qlo, int l32, int pm,
                                          bool last, float& m, float& l, f32x16* acc) {
  const float sc = 0.08838834764831845f * 1.4426950408889634f;  // 1/sqrt(128)*log2(e)
  bool do1 = !last || (qlo & 32);          // second 32-key block present?
  bool mask0 = last && !(qlo & 32);
  bool mask1 = last && (qlo & 32);
  int q = qlo + l32;
  // ---- QK^T: S^T[key][q], A = K, B = Q^T (aq) ----
  f32x16 s0 = {}, s1 = {};
#pragma unroll
  for (int t = 0; t < 8; ++t) {
    bf16x8 kf = *(const bf16x8*)&kg[(long)(kt * 64 + l32) * HD + t * 16 + pm * 8];
    s0 = __builtin_amdgcn_mfma_f32_32x32x16_bf16(kf, aq[t], s0, 0, 0, 0);
  }
  if (do1) {
#pragma unroll
    for (int t = 0; t < 8; ++t) {
      bf16x8 kf = *(const bf16x8*)&kg[(long)(kt * 64 + 32 + l32) * HD + t * 16 + pm * 8];
      s1 = __builtin_amdgcn_mfma_f32_32x32x16_bf16(kf, aq[t], s1, 0, 0, 0);
    }
  }
  // ---- scale + causal mask (diagonal block only) ----
#pragma unroll
  for (int i = 0; i < 16; ++i) {
    float v = s0[i] * sc;
    if (mask0) { int key = kt * 64 + (i & 3) + 8 * (i >> 2) + 4 * pm; v = (key > q) ? NEG_INF : v; }
    s0[i] = v;
  }
  if (do1) {
#pragma unroll
    for (int i = 0; i < 16; ++i) {
      float v = s1[i] * sc;
      if (mask1) { int key = kt * 64 + 32 + (i & 3) + 8 * (i >> 2) + 4 * pm; v = (key > q) ? NEG_INF : v; }
      s1[i] = v;
    }
  }
  // ---- online softmax (per-lane q) ----
  float mx = s0[0];
#pragma unroll
  for (int i = 1; i < 16; ++i) mx = fmaxf(mx, s0[i]);
  if (do1) {
#pragma unroll
    for (int i = 0; i < 16; ++i) mx = fmaxf(mx, s1[i]);
  }
  mx = fmaxf(mx, __shfl_xor(mx, 32));
  float mnew = fmaxf(m, mx);
  float alpha = exp2f(m - mnew);
  float sum = 0.f;
  uint32_t pk0[8], pk1[8];
#pragma unroll
  for (int i = 0; i < 8; ++i) {
    float a = exp2f(s0[2 * i] - mnew), b = exp2f(s0[2 * i + 1] - mnew);
    sum += a + b;
    pk0[i] = pack2bf(a, b);
  }
  if (do1) {
#pragma unroll
    for (int i = 0; i < 8; ++i) {
      float a = exp2f(s1[2 * i] - mnew), b = exp2f(s1[2 * i + 1] - mnew);
      sum += a + b;
      pk1[i] = pack2bf(a, b);
    }
  }
  sum += __shfl_xor(sum, 32);
  l = l * alpha + sum;
  m = mnew;
#pragma unroll
  for (int db = 0; db < 4; ++db)
#pragma unroll
    for (int i = 0; i < 16; ++i) acc[db][i] *= alpha;
  // ---- PV: acc^T += V^T * P^T. B-frag(P^T) built via xor-32 register exchange ----
#pragma unroll
  for (int ks = 0; ks < 4; ++ks) {
    if (ks < 2 || do1) {
      int a = ks & 1;
      uint32_t x0 = (ks >> 1) ? pk1[4 * a + 0] : pk0[4 * a + 0];
      uint32_t x1 = (ks >> 1) ? pk1[4 * a + 1] : pk0[4 * a + 1];
      uint32_t x2 = (ks >> 1) ? pk1[4 * a + 2] : pk0[4 * a + 2];
      uint32_t x3 = (ks >> 1) ? pk1[4 * a + 3] : pk0[4 * a + 3];
      uint32_t own0 = pm ? x2 : x0, own1 = pm ? x3 : x1;
      uint32_t snd0 = pm ? x0 : x2, snd1 = pm ? x1 : x3;
      uint32_t r0 = (uint32_t)__shfl_xor((int)snd0, 32);
      uint32_t r1 = (uint32_t)__shfl_xor((int)snd1, 32);
      union { uint32_t u[4]; bf16x8 v; } pf;
      pf.u[0] = pm ? r0 : own0;  pf.u[1] = pm ? r1 : own1;
      pf.u[2] = pm ? own0 : r0;  pf.u[3] = pm ? own1 : r1;
#pragma unroll
      for (int db = 0; db < 4; ++db) {
        bf16x8 vf = *(const bf16x8*)&vg[(long)(db * 32 + l32) * SQ + kt * 64 + ks * 16 + pm * 8];
        acc[db] = __builtin_amdgcn_mfma_f32_32x32x16_bf16(vf, pf.v, acc[db], 0, 0, 0);
      }
    }
  }
}

__global__ __launch_bounds__(256, 2) void attn(const short* __restrict__ q, const short* __restrict__ k,
                                               const short* __restrict__ vT, short* __restrict__ ctx) {
  int b = blockIdx.x;
  int g = b & 7;                           // XCD-pinned group
  int h = g * 4 + ((b >> 3) & 3);
  int w = threadIdx.x >> 6, lane = threadIdx.x & 63;
  int l32 = lane & 31, pm = lane >> 5;
  int strip = (15 - (b >> 5)) * 4 + w;     // LPT: longest strips dispatched first
  int qlo = strip * 32;
  const short* qh = q + (long)h * SQ * HD;
  const short* kg = k + (long)g * SQ * HD;
  const short* vg = vT + (long)g * HD * SQ;
  // Q^T B-frags: lane holds Q[q = qlo+l32][t*16 + pm*8 .. +7]
  bf16x8 aq[8];
#pragma unroll
  for (int t = 0; t < 8; ++t)
    aq[t] = *(const bf16x8*)&qh[(long)(qlo + l32) * HD + t * 16 + pm * 8];
  float m = NEG_INF, l = 0.f;
  f32x16 acc[4] = {};
  int nkt = ((qlo + 31) >> 6) + 1;
  for (int kt = 0; kt < nkt; ++kt)
    attn_step(kg, vg, aq, kt, qlo, l32, pm, kt == nkt - 1, m, l, acc);
  // ---- epilogue: xor-32 repack -> 16B stores, ctx[s][h*128+d] ----
  float inv = 1.0f / l;
#pragma unroll
  for (int db = 0; db < 4; ++db) {
    uint32_t ou[8];
#pragma unroll
    for (int i = 0; i < 8; ++i)
      ou[i] = pack2bf(acc[db][2 * i] * inv, acc[db][2 * i + 1] * inv);
#pragma unroll
    for (int c = 0; c < 4; ++c) {
      uint32_t o0 = ou[2 * c], o1 = ou[2 * c + 1];
      uint32_t r0 = (uint32_t)__shfl_xor((int)o0, 32);
      uint32_t r1 = (uint32_t)__shfl_xor((int)o1, 32);
      uint4 st;
      st.x = pm ? r0 : o0;  st.y = pm ? r1 : o1;
      st.z = pm ? o0 : r0;  st.w = pm ? o1 : r1;
      *(uint4*)&ctx[(long)(qlo + l32) * DIN + h * HD + db * 32 + c * 8] = st;
    }
  }
}

// ---------------- workspace layout (round-2) ----------------
#define XB_OFF     0L
#define QR_OFF     0L
#define WQKVT_OFF  16777216L
#define KR_OFF     16777216L
#define VT_OFF     20971520L
#define CTX_OFF    25165824L
#define WOT_OFF    67108864L
#define QKV_OFF    100663296L

extern "C" void kernel_launch(void* const* d_in, const int* in_sizes, int n_in,
                              void* d_out, int out_size, void* d_ws, size_t ws_size,
                              hipStream_t stream) {
  const float* x    = (const float*)d_in[0];
  const float* cosb = (const float*)d_in[2];
  const float* sinb = (const float*)d_in[3];
  const float* Wq   = (const float*)d_in[4];
  const float* Wk   = (const float*)d_in[5];
  const float* Wv   = (const float*)d_in[6];
  const float* Wo   = (const float*)d_in[7];
  const float* qnw  = (const float*)d_in[8];
  const float* qnb  = (const float*)d_in[9];
  const float* knw  = (const float*)d_in[10];
  const float* knb  = (const float*)d_in[11];

  char* ws = (char*)d_ws;
  short* xb    = (short*)(ws + XB_OFF);
  short* qr    = (short*)(ws + QR_OFF);
  short* wqkvt = (short*)(ws + WQKVT_OFF);
  short* krp   = (short*)(ws + KR_OFF);
  short* vt    = (short*)(ws + VT_OFF);
  short* ctx   = (short*)(ws + CTX_OFF);
  short* wot   = (short*)(ws + WOT_OFF);
  float* qkv   = (float*)(ws + QKV_OFF);

  cvt_bf16<<<8192, 256, 0, stream>>>(x, xb, (long)SQ * DIN);
  transpose_cvt<<<dim3(64, 64, 1), 256, 0, stream>>>(Wq, 4096, 0L, wqkvt, 4096, 0L);
  transpose_cvt<<<dim3(16, 64, 1), 256, 0, stream>>>(Wk, 1024, 0L, wqkvt + (long)4096 * 4096, 4096, 0L);
  transpose_cvt<<<dim3(16, 64, 1), 256, 0, stream>>>(Wv, 1024, 0L, wqkvt + (long)5120 * 4096, 4096, 0L);
  transpose_cvt<<<dim3(64, 64, 1), 256, 0, stream>>>(Wo, 4096, 0L, wot, 4096, 0L);
  gemm_bf16<<<dim3(NQKV / BN, SQ / BM), 256, 0, stream>>>(xb, wqkvt, qkv, SQ, NQKV, DIN);
  ln_rope<<<dim3(SQ, NH + NKV), 64, 0, stream>>>(qkv, cosb, sinb, qnw, qnb, knw, knb, qr, krp);
  transpose_cvt<<<dim3(2, 32, 8), 256, 0, stream>>>(qkv + 5120, NQKV, 128L, vt, SQ, (long)HD * SQ);
  attn<<<dim3(512), 256, 0, stream>>>(qr, krp, vt, ctx);
  gemm_bf16<<<dim3(DIN / BN, SQ / BM), 256, 0, stream>>>(ctx, wot, (float*)d_out, SQ, DIN, DIN);
}